// Round 4
// baseline (190.317 us; speedup 1.0000x reference)
//
#include <hip/hip_runtime.h>

// ---------------------------------------------------------------------------
// SelfAttentionLayer: out[b,s,c*16+h] = softmax_k( (q.k)/32 masked ) @ v
// R10: eliminate the 210 MB cast_all X round-trip (~35-40 us). The fused
// kernel now reads f32 X directly and converts during staging:
//   global_load_dwordx4 (f32) -> v_cvt_pk_bf16_f32 -> swizzled ds_write_b128.
// W keeps gload16 DMA from a tiny W-only cast kernel (18 MB, ~3 us).
// GEMM schedule stays R8's proven single-Xs BK=64 / 2-barriers-per-iter
// (R9 proved pipelined BK=32 loses: barrier count doubles on a bytes-bound
// phase). Ws is double-buffered so its DMA for t+1 issues at iter-t top and
// is covered by the tail vmcnt(0) that also waits the X register loads.
// ---------------------------------------------------------------------------

typedef unsigned short u16;
typedef unsigned int u32;
typedef __attribute__((ext_vector_type(8))) short short8;
typedef __attribute__((ext_vector_type(4))) short short4v;
typedef __attribute__((ext_vector_type(4))) float floatx4;

#if __has_builtin(__builtin_amdgcn_mfma_f32_16x16x16bf16_1k)
#define MFMA16(A, B, C) __builtin_amdgcn_mfma_f32_16x16x16bf16_1k(A, B, C, 0, 0, 0)
#elif __has_builtin(__builtin_amdgcn_mfma_f32_16x16x16_bf16)
#define MFMA16(A, B, C) __builtin_amdgcn_mfma_f32_16x16x16_bf16(A, B, C, 0, 0, 0)
#else
__device__ __forceinline__ floatx4 mfma16_asm(short4v a, short4v b, floatx4 c) {
  floatx4 d;
  asm volatile("v_mfma_f32_16x16x16_bf16 %0, %1, %2, %3"
               : "=v"(d) : "v"(a), "v"(b), "v"(c));
  return d;
}
#define MFMA16(A, B, C) mfma16_asm(A, B, C)
#endif

#if __has_builtin(__builtin_amdgcn_exp2f)
#define EXP2(x) __builtin_amdgcn_exp2f(x)
#else
#define EXP2(x) __expf((x) * 0.6931471805599453f)
#endif

#define QSCALE 0.045084220f  // log2(e)/32, folded into Q

__device__ __forceinline__ u16 f2bf(float f) {
  union { float f; u32 u; } x; x.f = f;
  u32 r = x.u + 0x7fffu + ((x.u >> 16) & 1u);  // RNE
  return (u16)(r >> 16);
}
__device__ __forceinline__ float bf2f(u16 u) {
  union { u32 u; float f; } x; x.u = ((u32)u) << 16;
  return x.f;
}

// packed f32 pair -> bf16 pair (RNE), low half = first operand
__device__ __forceinline__ u32 pkbf(float lo, float hi) {
  u32 d;
  asm("v_cvt_pk_bf16_f32 %0, %1, %2" : "=v"(d) : "v"(lo), "v"(hi));
  return d;
}

// async global->LDS, 16B per lane; LDS dest = wave-uniform base + lane*16
__device__ __forceinline__ void gload16(const void* g, void* l) {
  typedef __attribute__((address_space(1))) const unsigned int gq;
  typedef __attribute__((address_space(3))) unsigned int lq;
  __builtin_amdgcn_global_load_lds((gq*)(size_t)g, (lq*)(size_t)l, 16, 0, 0);
}

#define GK 1024
#define QKS 20   // Qs/Ks row stride (u16): 8B-aligned frags, conflict-free
#define VTS 264  // Vt row stride (u16): 2-way-max banks (free)

// ---------------------------------------------------------------------------
// W-only cast f32 -> bf16: Wq/Wk/Wv, 1024 blocks each (18 MB total, ~3 us)
// ---------------------------------------------------------------------------
__global__ __launch_bounds__(256) void cast_w(const float* __restrict__ wq,
                                              const float* __restrict__ wk,
                                              const float* __restrict__ wv,
                                              u16* __restrict__ WB) {
  int bid = blockIdx.x;
  const float* src = (bid < 1024) ? wq : (bid < 2048) ? wk : wv;
  int seg = bid >> 10;                       // 0,1,2
  int i = ((bid & 1023) * 256 + threadIdx.x) * 4;
  float4 v = *(const float4*)(src + i);
  uint2 o;
  o.x = pkbf(v.x, v.y);
  o.y = pkbf(v.z, v.w);
  *(uint2*)(WB + (size_t)seg * 1024 * 1024 + i) = o;
}

// ---------------------------------------------------------------------------
// Attn kt-loop (R5-verified math, LDS sources): S^T = MFMA(K, Qscaled);
// p = exp2(st) trunc-packed via v_perm; l via MFMA(ones,p); O^T += MFMA(V^T,p)
// qt=2: each of the 8 waves owns a 32-row q-strip.
// ---------------------------------------------------------------------------
template <bool MASKED>
__device__ __forceinline__ void attn_loop2(const u16* __restrict__ Ks,
                                           const u16* __restrict__ Vt,
                                           const short4v* bq, const float* mqv,
                                           const float* m_s,
                                           floatx4* oacc, floatx4* lacc,
                                           int col, int quad) {
  const short4v ones = {(short)0x3F80, (short)0x3F80, (short)0x3F80, (short)0x3F80};
#pragma unroll 4
  for (int kt = 0; kt < 16; kt++) {
    const int kb = kt * 16;
    short4v ak = *(const short4v*)(Ks + (kb + col) * QKS + quad * 4);
    short4v av = *(const short4v*)(Vt + col * VTS + kb + quad * 4);
    float mk[4];
    if (MASKED) {
#pragma unroll
      for (int i = 0; i < 4; i++) mk[i] = m_s[kb + quad * 4 + i];
    }
#pragma unroll
    for (int qt = 0; qt < 2; qt++) {
      floatx4 z = {0.f, 0.f, 0.f, 0.f};
      floatx4 st = MFMA16(ak, bq[qt], z);
      float e[4];
#pragma unroll
      for (int i = 0; i < 4; i++) {
        e[i] = EXP2(st[i]);
        if (MASKED) e[i] = (mqv[qt] * mk[i] > 0.f) ? e[i] : 0.f;
      }
      union { u32 u[2]; short4v s; } pk;
      pk.u[0] = __builtin_amdgcn_perm(__float_as_uint(e[1]), __float_as_uint(e[0]), 0x07060302u);
      pk.u[1] = __builtin_amdgcn_perm(__float_as_uint(e[3]), __float_as_uint(e[2]), 0x07060302u);
      lacc[qt] = MFMA16(ones, pk.s, lacc[qt]);
      oacc[qt] = MFMA16(av, pk.s, oacc[qt]);
    }
  }
}

// ---------------------------------------------------------------------------
// Fused kernel. Block = (c0 = (bid>>5)*2 heads, b = bid&31); grid 1024.
// Same-b blocks -> same XCD (bid%8 = b%8): X[b] f32 (1 MB) stays L2-resident.
// Phase 1 (GEMM): [256,96] = X[b][256,1024](f32, cast in-flight) @ W[96]^T.
//   Per iter t: [A barrier] -> issue W-DMA(t+1, Ws[!p]) + 8 X f32 loads(t+1)
//   -> 8 ds_read_b128 + 24 MFMA (tile t) -> lgkm(0) -> [B barrier] ->
//   vmcnt(0) -> 16 cvt_pk + 4 swizzled ds_write_b128 (Xs = t+1) -> lgkm(0).
//   Swizzle (R8-proven, 128 B rows): phys 16 B chunk p of row r holds
//   logical p^(r&7); read chunk = (kk*4+quad)^(col&7).
// Phase 2 (x2 heads, sequential): identical to R8.
// LDS: Xs[256][64]@0 (32 KB) + Ws 2x[96][64] @32768/@45056 = 56 KB; attn
// (29.3 KB) overlays Xs; +1 KB m_s = ~58.4 KB -> 2 blocks/CU.
// ---------------------------------------------------------------------------
__global__ __launch_bounds__(512, 4) void fused_qkv_attn(const float* __restrict__ x,
                                                         const u16* __restrict__ WB,
                                                         const float* __restrict__ mask,
                                                         float* __restrict__ out) {
  __shared__ __align__(16) u16 smem[28672];  // 57344 B
  // GEMM: Xs@0 (256*64), WsA@16384 (96*64), WsB@22528
  // attn: Qs@0 (256*20), Ks@5120, Vt@10240 (16*264), l_s@14464 (256 f32),
  //       ot overlays @0 (16*257 f32) -- all inside Xs region
  __shared__ float m_s[256];

  const int bid = blockIdx.x;
  const int b = bid & 31;
  const int c0 = (bid >> 5) * 2;       // first of 2 heads
  const int t = threadIdx.x;
  const int wave = t >> 6;             // 0..7
  const int lane = t & 63;
  const int col = lane & 15;
  const int quad = lane >> 4;

  u16* const Xs = smem;
  u16* const WsA = smem + 16384;
  u16* const WsB = smem + 22528;

  float mv = (t < 256) ? mask[b * 256 + t] : 1.0f;
  if (t < 256) m_s[t] = mv;
  const int allones = __syncthreads_and(mv > 0.f);

  // ---------------- phase 1: GEMM with in-flight X cast ----------------
  // X reg-staging: thread covers row (t>>3)+64p (p=0..3), f32 chunk t&7
  // (8 cols). Loads: 16 consecutive lanes read a contiguous 256 B row slice.
  const float* const xg = x + ((size_t)b * 256 + (t >> 3)) * GK + (t & 7) * 8;
  // swizzled LDS dest (u16 units): row*64 + (chunk^(row&7))*8; +p*4096
  const int wbase = (t >> 3) * 64 + (((t & 7) ^ ((t >> 3) & 7)) * 8);

  // W DMA (R8 BK=64 staging verbatim): 12 groups of 8 rows x 8 chunks
  const int r_loc8 = lane >> 3;            // row within 8-row group
  const int sch8 = (lane & 7) ^ r_loc8;    // XOR-swizzled source chunk
  const int gA = wave;
  const int ntA = gA >> 1;
  const size_t wsrcA =
      ((size_t)((ntA % 3) * 1024 + (c0 + ntA / 3) * 16 + (gA & 1) * 8 + r_loc8)) * GK + sch8 * 8;
  size_t wsrcB = 0;
  const int gB = 8 + wave;
  if (wave < 4) {
    const int ntB = gB >> 1;
    wsrcB = ((size_t)((ntB % 3) * 1024 + (c0 + ntB / 3) * 16 + (gB & 1) * 8 + r_loc8)) * GK + sch8 * 8;
  }

  floatx4 acc[2][6] = {};  // [mt][nt]: m = wave*32+mt*16; nt = head*3+{Q,K,V}
  float4 xv[8];            // in-flight X f32 (statically indexed everywhere)

  // prologue: W(0) -> WsA; X(0) -> regs -> Xs
  gload16(WB + wsrcA, WsA + gA * 512);
  if (wave < 4) gload16(WB + wsrcB, WsA + gB * 512);
#pragma unroll
  for (int p = 0; p < 4; p++) {
#pragma unroll
    for (int q = 0; q < 2; q++)
      xv[p * 2 + q] = *(const float4*)(xg + p * 65536 + q * 4);
  }
  asm volatile("s_waitcnt vmcnt(0)" ::: "memory");  // X regs + W(0) landed
#pragma unroll
  for (int p = 0; p < 4; p++) {
    uint4 w;
    w.x = pkbf(xv[p * 2].x, xv[p * 2].y);
    w.y = pkbf(xv[p * 2].z, xv[p * 2].w);
    w.z = pkbf(xv[p * 2 + 1].x, xv[p * 2 + 1].y);
    w.w = pkbf(xv[p * 2 + 1].z, xv[p * 2 + 1].w);
    *(uint4*)(Xs + wbase + p * 4096) = w;
  }
  asm volatile("s_waitcnt lgkmcnt(0)" ::: "memory");
  __builtin_amdgcn_sched_barrier(0);

  auto gemm_step = [&](int tnext, const u16* Wc, u16* Wn) {
    __builtin_amdgcn_s_barrier();      // tile visible to all waves
    __builtin_amdgcn_sched_barrier(0);

    if (tnext >= 0) {
      const int k0n = tnext * 64;
      gload16(WB + wsrcA + k0n, Wn + gA * 512);
      if (wave < 4) gload16(WB + wsrcB + k0n, Wn + gB * 512);
#pragma unroll
      for (int p = 0; p < 4; p++) {
#pragma unroll
        for (int q = 0; q < 2; q++)
          xv[p * 2 + q] = *(const float4*)(xg + k0n + p * 65536 + q * 4);
      }
    }

    // compute current tile (R8-proven fragment path)
#pragma unroll
    for (int kk = 0; kk < 2; kk++) {
      const int pos = ((kk * 4 + quad) ^ (col & 7)) * 8;
      short8 af[2], bf[6];
#pragma unroll
      for (int mt = 0; mt < 2; mt++)
        af[mt] = *(const short8*)(Xs + (wave * 32 + mt * 16 + col) * 64 + pos);
#pragma unroll
      for (int nt = 0; nt < 6; nt++)
        bf[nt] = *(const short8*)(Wc + (nt * 16 + col) * 64 + pos);
#pragma unroll
      for (int mt = 0; mt < 2; mt++)
#pragma unroll
        for (int nt = 0; nt < 6; nt++)
          acc[mt][nt] = __builtin_amdgcn_mfma_f32_16x16x32_bf16(af[mt], bf[nt], acc[mt][nt], 0, 0, 0);
    }

    asm volatile("s_waitcnt lgkmcnt(0)" ::: "memory");  // my ds_reads done
    __builtin_amdgcn_sched_barrier(0);
    __builtin_amdgcn_s_barrier();      // ALL reads of Xs/Wc done
    __builtin_amdgcn_sched_barrier(0);

    if (tnext >= 0) {
      asm volatile("s_waitcnt vmcnt(0)" ::: "memory");  // X regs + W DMA landed
#pragma unroll
      for (int p = 0; p < 4; p++) {
        uint4 w;
        w.x = pkbf(xv[p * 2].x, xv[p * 2].y);
        w.y = pkbf(xv[p * 2].z, xv[p * 2].w);
        w.z = pkbf(xv[p * 2 + 1].x, xv[p * 2 + 1].y);
        w.w = pkbf(xv[p * 2 + 1].z, xv[p * 2 + 1].w);
        *(uint4*)(Xs + wbase + p * 4096) = w;
      }
      asm volatile("s_waitcnt lgkmcnt(0)" ::: "memory");  // writes visible
      __builtin_amdgcn_sched_barrier(0);
    }
  };

  // tiles 0..15; W tile t in WsA when t even
#pragma unroll 1
  for (int tp = 0; tp < 8; tp++) {
    gemm_step(2 * tp + 1, WsA, WsB);                  // t = 2tp
    gemm_step((tp == 7) ? -1 : 2 * tp + 2, WsB, WsA); // t = 2tp+1
  }

  // ---------------- phase 2: attention, 2 heads sequentially ----------------
  u16* const Qs = smem;               // [256][QKS]
  u16* const Ks = smem + 5120;        // [256][QKS]
  u16* const Vt = smem + 10240;       // [16][VTS]
  float* const l_s = (float*)(smem + 14464);
  float* const ot = (float*)smem;     // [16][257] f32, overlays Qs+Ks

#pragma unroll      // full unroll: h must be compile-time (static acc indices)
  for (int h = 0; h < 2; h++) {
    __syncthreads();  // h=0: GEMM reads done; h=1: prev ot/Vt reads done

    // C/D layout: row = m-base + quad*4 + r, col(head feature) = lane&15
#pragma unroll
    for (int mt = 0; mt < 2; mt++) {
      const int row = wave * 32 + mt * 16 + quad * 4;
#pragma unroll
      for (int r = 0; r < 4; r++) {
        Qs[(row + r) * QKS + col] = f2bf(acc[mt][3 * h + 0][r] * QSCALE);
        Ks[(row + r) * QKS + col] = f2bf(acc[mt][3 * h + 1][r]);
        Vt[col * VTS + row + r] = f2bf(acc[mt][3 * h + 2][r]);
      }
    }
    __syncthreads();

    const int q0 = wave * 32;
    short4v bq[2];
    float mqv[2];
#pragma unroll
    for (int qt = 0; qt < 2; qt++) {
      bq[qt] = *(const short4v*)(Qs + (q0 + qt * 16 + col) * QKS + quad * 4);
      mqv[qt] = m_s[q0 + qt * 16 + col];
    }

    floatx4 oacc[2] = {};
    floatx4 lacc[2] = {};
    if (allones)
      attn_loop2<false>(Ks, Vt, bq, mqv, m_s, oacc, lacc, col, quad);
    else
      attn_loop2<true>(Ks, Vt, bq, mqv, m_s, oacc, lacc, col, quad);

    __syncthreads();  // all waves out of attn before ot overlays Qs/Ks
#pragma unroll
    for (int qt = 0; qt < 2; qt++) {
      if (quad == 0) l_s[q0 + qt * 16 + col] = lacc[qt][0];
#pragma unroll
      for (int r = 0; r < 4; r++)
        ot[(quad * 4 + r) * 257 + q0 + qt * 16 + col] = oacc[qt][r];
    }
    __syncthreads();

    // epilogue: thread t -> q-row t>>1, features hb..hb+8; 32B coalesced
    const int row = t >> 1;
    const int hb = (t & 1) * 8;
    float l = l_s[row];
    float* op = out + ((size_t)b * 256 + row) * 1024 + (c0 + h) * 16 + hb;
    float o[8];
    if (allones || l > 0.f) {
      float inv = 1.0f / l;
#pragma unroll
      for (int j = 0; j < 8; j++) o[j] = ot[(hb + j) * 257 + row] * inv;
    } else {
      // fully-masked row: reference softmax of uniform -1e9 -> mean of V
#pragma unroll
      for (int j = 0; j < 8; j++) o[j] = 0.f;
      for (int k = 0; k < 256; k++)
#pragma unroll
        for (int j = 0; j < 8; j++) o[j] += bf2f(Vt[(hb + j) * VTS + k]);
#pragma unroll
      for (int j = 0; j < 8; j++) o[j] *= (1.0f / 256.0f);
    }
#pragma unroll
    for (int g = 0; g < 2; g++) {
      float4 r;
      r.x = o[g * 4 + 0]; r.y = o[g * 4 + 1]; r.z = o[g * 4 + 2]; r.w = o[g * 4 + 3];
      *(float4*)(op + g * 4) = r;
    }
  }
}

// ---------------------------------------------------------------------------
// Launch
// ---------------------------------------------------------------------------
extern "C" void kernel_launch(void* const* d_in, const int* in_sizes, int n_in,
                              void* d_out, int out_size, void* d_ws, size_t ws_size,
                              hipStream_t stream) {
  const float* x    = (const float*)d_in[0];  // [32,256,1024]
  const float* mask = (const float*)d_in[1];  // [32,256]
  const float* Wq   = (const float*)d_in[2];  // [1024,1024]
  const float* Wk   = (const float*)d_in[3];
  const float* Wv   = (const float*)d_in[4];
  float* out = (float*)d_out;

  u16* WB = (u16*)d_ws;                       // [3072][1024] bf16 (Wq,Wk,Wv)

  cast_w<<<3072, 256, 0, stream>>>(Wq, Wk, Wv, WB);
  fused_qkv_attn<<<1024, 512, 0, stream>>>(x, WB, mask, out);
}